// Round 10
// baseline (308.193 us; speedup 1.0000x reference)
//
#include <hip/hip_runtime.h>

#define BM 64

typedef __bf16 bf16x8 __attribute__((ext_vector_type(8)));
typedef float f32x4 __attribute__((ext_vector_type(4)));
typedef float f4 __attribute__((ext_vector_type(4)));

__device__ __forceinline__ unsigned short f2bf(float x) {
  unsigned int u = __builtin_bit_cast(unsigned int, x);
  u += 0x7fffu + ((u >> 16) & 1u);   // RTNE
  return (unsigned short)(u >> 16);
}

__device__ __forceinline__ float bf1f(unsigned short x) {
  return __builtin_bit_cast(float, (unsigned)x << 16);
}

__device__ __forceinline__ int swz(int row, int col) {
  return (row * 128 + col) ^ ((row & 7) << 3);
}

__device__ __forceinline__ f4 ntload4(const float* p) {
  return __builtin_nontemporal_load((const f4*)p);
}

// 4 bf16 (as ushort4) -> 4 floats
__device__ __forceinline__ f4 bf4f(const unsigned short* p) {
  ushort4 v = *(const ushort4*)p;
  f4 r;
  r.x = bf1f(v.x); r.y = bf1f(v.y); r.z = bf1f(v.z); r.w = bf1f(v.w);
  return r;
}

__device__ __forceinline__ int wave_incl_scan(int v, int lane) {
  #pragma unroll
  for (int off = 1; off < 64; off <<= 1) {
    int t = __shfl_up(v, off, 64);
    if (lane >= off) v += t;
  }
  return v;
}

// ---- weights -> bf16 transposed; zero dst-degree counters ----
__global__ __launch_bounds__(256) void prep_weights(
    const float* __restrict__ W1, const float* __restrict__ W2,
    unsigned short* __restrict__ W1T, unsigned short* __restrict__ W2T,
    int* __restrict__ counts, int N) {
  int t = blockIdx.x * 256 + threadIdx.x;  // 0..65535
  if (t < N) counts[t] = 0;
  {  // W1 [128][512] -> W1T[h][k]
    int hh = t >> 7, kk = t & 127;
    W1T[t] = f2bf(W1[kk * 512 + hh]);
  }
  {  // W2 [512][128] -> W2T[d][h]
    int dd = t >> 9, hh = t & 511;
    W2T[t] = f2bf(W2[hh * 128 + dd]);
  }
}

// ---- h -> bf16 table, fused with dst histogram (counts pre-zeroed) ----
__global__ __launch_bounds__(256) void h2bf_hist(
    const float* __restrict__ h, unsigned short* __restrict__ hb,
    const int* __restrict__ dst, int* __restrict__ counts, int q4, int E) {
  int i = blockIdx.x * 256 + threadIdx.x;   // one f4 (4 elements) per thread
  if (i < q4) {
    f4 v = *(const f4*)(h + (size_t)i * 4);
    ushort4 o;
    o.x = f2bf(v.x); o.y = f2bf(v.y); o.z = f2bf(v.z); o.w = f2bf(v.w);
    *(ushort4*)(hb + (size_t)i * 4) = o;
  }
  if (i < E) atomicAdd(&counts[dst[i]], 1);
}

// ---- single-workgroup exclusive scan: counts[0..N) -> offs[0..N) ----
__global__ __launch_bounds__(1024) void scan_all(const int* __restrict__ counts,
                                                 int* __restrict__ offs, int N) {
  __shared__ int wsum[16];
  const int tid = threadIdx.x, lane = tid & 63, wv = tid >> 6;
  const int per = (N + 1023) >> 10;
  int b0 = tid * per, b1 = b0 + per;
  if (b0 > N) b0 = N;
  if (b1 > N) b1 = N;
  int s = 0;
  for (int i = b0; i < b1; ++i) s += counts[i];
  int incl = wave_incl_scan(s, lane);
  if (lane == 63) wsum[wv] = incl;
  __syncthreads();
  int wpre = 0;
  for (int w = 0; w < wv; ++w) wpre += wsum[w];
  int excl = wpre + incl - s;
  for (int i = b0; i < b1; ++i) { offs[i] = excl; excl += counts[i]; }
}

// bumps offs[] to row-end; gather recovers beg = end - cnt.
// perm2[p] = (edge index, src node) so the gather never chases src[].
__global__ __launch_bounds__(256) void build_perm(const int* __restrict__ dst,
                                                  const int* __restrict__ src,
                                                  int* offs, int2* perm2, int E) {
  int i = blockIdx.x * 256 + threadIdx.x;
  if (i < E) {
    int p = atomicAdd(&offs[dst[i]], 1);
    perm2[p] = make_int2(i, src[i]);
  }
}

// ---- ub[n] = bf16( sum over edges e with dst==n of (h[src[e]] + e_ij[e]) )
// Round-6 structure (known good): one wave per node, wave-uniform shfl
// bounds, 8-wide main loop. h read from the bf16 table (256B/row).
__global__ __launch_bounds__(256) void gather_sum(
    const unsigned short* __restrict__ hb, const float* __restrict__ eij,
    const int2* __restrict__ perm2,
    const int* __restrict__ offs, const int* __restrict__ counts,
    unsigned short* __restrict__ ub, int N) {
  int node = blockIdx.x * 4 + (threadIdx.x >> 6);
  if (node >= N) return;                               // wave-uniform
  int lane = threadIdx.x & 63;
  int half = lane >> 5, c4 = (lane & 31) * 4;
  int cnt = counts[node];
  int beg = offs[node] - cnt;                          // offs holds end after build_perm
  f4 acc = (f4){0.f, 0.f, 0.f, 0.f};
  for (int base = 0; base < cnt; base += 64) {
    int m = cnt - base; if (m > 64) m = 64;            // wave-uniform
    int2 es = perm2[beg + base + (lane < m ? lane : m - 1)];
    int k = 0;
    // main: 8 edges (4 per half) all provably in range for BOTH halves
    for (; 2 * k + 8 <= m; k += 4) {                   // uniform condition
      int i0 = 2 * k + half;
      int e0 = __shfl(es.x, i0, 64),     s0 = __shfl(es.y, i0, 64);
      int e1 = __shfl(es.x, i0 + 2, 64), s1 = __shfl(es.y, i0 + 2, 64);
      int e2 = __shfl(es.x, i0 + 4, 64), s2 = __shfl(es.y, i0 + 4, 64);
      int e3 = __shfl(es.x, i0 + 6, 64), s3 = __shfl(es.y, i0 + 6, 64);
      f4 ev0 = ntload4(eij + (size_t)e0 * 128 + c4);
      f4 ev1 = ntload4(eij + (size_t)e1 * 128 + c4);
      f4 ev2 = ntload4(eij + (size_t)e2 * 128 + c4);
      f4 ev3 = ntload4(eij + (size_t)e3 * 128 + c4);
      f4 hv0 = bf4f(hb + (size_t)s0 * 128 + c4);
      f4 hv1 = bf4f(hb + (size_t)s1 * 128 + c4);
      f4 hv2 = bf4f(hb + (size_t)s2 * 128 + c4);
      f4 hv3 = bf4f(hb + (size_t)s3 * 128 + c4);
      acc += (ev0 + hv0) + (ev1 + hv1) + (ev2 + hv2) + (ev3 + hv3);
    }
    // tail: uniform loop; shfl by all lanes, loads predicated
    for (; 2 * k < m; ++k) {                           // uniform condition
      int idx = 2 * k + half;
      int e = __shfl(es.x, idx & 63, 64), s = __shfl(es.y, idx & 63, 64);
      if (idx < m) {                                   // load-only divergence
        f4 ev = ntload4(eij + (size_t)e * 128 + c4);
        f4 hv = bf4f(hb + (size_t)s * 128 + c4);
        acc += ev + hv;
      }
    }
  }
  acc.x += __shfl_xor(acc.x, 32, 64);
  acc.y += __shfl_xor(acc.y, 32, 64);
  acc.z += __shfl_xor(acc.z, 32, 64);
  acc.w += __shfl_xor(acc.w, 32, 64);
  if (half == 0) {
    ushort4 o;
    o.x = f2bf(acc.x); o.y = f2bf(acc.y); o.z = f2bf(acc.z); o.w = f2bf(acc.w);
    *(ushort4*)(ub + (size_t)node * 128 + c4) = o;
  }
}

// ---- out = LN(relu(u@W1+b1)@W2 + b2 + h) * gamma + beta ----
// u read as bf16 from ub; residual h read as bf16 from hb.
__global__ __launch_bounds__(256, 2) void fused_mlp_ln(
    const unsigned short* __restrict__ ub, const unsigned short* __restrict__ hb,
    const unsigned short* __restrict__ W1T, const unsigned short* __restrict__ W2T,
    const float* __restrict__ b1, const float* __restrict__ b2,
    const float* __restrict__ gma, const float* __restrict__ bta,
    float* __restrict__ out, int N) {
  __shared__ unsigned short As[BM * 128];
  __shared__ unsigned short Hs[BM * 128];
  __shared__ unsigned short Bs[128 * 128];

  const int tid = threadIdx.x;
  const int wave = tid >> 6, lane = tid & 63;
  const int lo = lane & 15, hi = lane >> 4;
  const int bm0 = blockIdx.x * BM;
  const int arow = wave * 16 + lo;

  #pragma unroll
  for (int i = 0; i < 8; ++i) {
    int q = i * 256 + tid;
    int r = q >> 5, c4 = (q & 31) * 4;
    ushort4 v = make_ushort4(0, 0, 0, 0);
    if (bm0 + r < N) v = *(const ushort4*)(ub + (size_t)(bm0 + r) * 128 + c4);
    *(ushort4*)(&As[swz(r, c4)]) = v;
  }

  f32x4 acc2[8];
  #pragma unroll
  for (int n = 0; n < 8; ++n) acc2[n] = (f32x4){0.f, 0.f, 0.f, 0.f};

  for (int c = 0; c < 4; ++c) {
    __syncthreads();
    #pragma unroll
    for (int i = 0; i < 8; ++i) {
      int q = i * 256 + tid;
      int r = q >> 4, c8 = (q & 15) * 8;
      uint4 w = *(const uint4*)(W1T + ((size_t)(c * 128 + r) * 128 + c8));
      *(uint4*)(&Bs[swz(r, c8)]) = w;
    }
    __syncthreads();

    f32x4 acc1[8];
    #pragma unroll
    for (int n = 0; n < 8; ++n) acc1[n] = (f32x4){0.f, 0.f, 0.f, 0.f};
    #pragma unroll
    for (int kk = 0; kk < 4; ++kk) {
      bf16x8 a = *(const bf16x8*)(&As[swz(arow, kk * 32 + hi * 8)]);
      #pragma unroll
      for (int n = 0; n < 8; ++n) {
        bf16x8 b = *(const bf16x8*)(&Bs[swz(n * 16 + lo, kk * 32 + hi * 8)]);
        acc1[n] = __builtin_amdgcn_mfma_f32_16x16x32_bf16(a, b, acc1[n], 0, 0, 0);
      }
    }
    #pragma unroll
    for (int n = 0; n < 8; ++n) {
      float bb = b1[c * 128 + n * 16 + lo];
      #pragma unroll
      for (int j = 0; j < 4; ++j) {
        float v = acc1[n][j] + bb;
        v = v > 0.f ? v : 0.f;
        Hs[swz(wave * 16 + hi * 4 + j, n * 16 + lo)] = f2bf(v);
      }
    }
    __syncthreads();
    #pragma unroll
    for (int i = 0; i < 8; ++i) {
      int q = i * 256 + tid;
      int r = q >> 4, c8 = (q & 15) * 8;
      uint4 w = *(const uint4*)(W2T + ((size_t)r * 512 + c * 128 + c8));
      *(uint4*)(&Bs[swz(r, c8)]) = w;
    }
    __syncthreads();
    #pragma unroll
    for (int kk = 0; kk < 4; ++kk) {
      bf16x8 a = *(const bf16x8*)(&Hs[swz(arow, kk * 32 + hi * 8)]);
      #pragma unroll
      for (int n = 0; n < 8; ++n) {
        bf16x8 b = *(const bf16x8*)(&Bs[swz(n * 16 + lo, kk * 32 + hi * 8)]);
        acc2[n] = __builtin_amdgcn_mfma_f32_16x16x32_bf16(a, b, acc2[n], 0, 0, 0);
      }
    }
  }

  float b2v[8], gv[8], bv2[8];
  #pragma unroll
  for (int n = 0; n < 8; ++n) {
    int d = n * 16 + lo;
    b2v[n] = b2[d]; gv[n] = gma[d]; bv2[n] = bta[d];
  }
  #pragma unroll
  for (int j = 0; j < 4; ++j) {
    int m = wave * 16 + hi * 4 + j;
    int grow = bm0 + m;
    bool valid = grow < N;
    float vals[8];
    float s = 0.f, s2 = 0.f;
    #pragma unroll
    for (int n = 0; n < 8; ++n) {
      float hres = valid ? bf1f(hb[(size_t)grow * 128 + n * 16 + lo]) : 0.f;
      float v = acc2[n][j] + b2v[n] + hres;
      vals[n] = v;
      s += v; s2 += v * v;
    }
    #pragma unroll
    for (int mk = 1; mk < 16; mk <<= 1) {
      s  += __shfl_xor(s, mk, 64);
      s2 += __shfl_xor(s2, mk, 64);
    }
    float mean = s * (1.f / 128.f);
    float var = s2 * (1.f / 128.f) - mean * mean;
    float inv = rsqrtf(var + 1e-5f);
    if (valid) {
      #pragma unroll
      for (int n = 0; n < 8; ++n) {
        out[(size_t)grow * 128 + n * 16 + lo] = (vals[n] - mean) * inv * gv[n] + bv2[n];
      }
    }
  }
}

extern "C" void kernel_launch(void* const* d_in, const int* in_sizes, int n_in,
                              void* d_out, int out_size, void* d_ws, size_t ws_size,
                              hipStream_t stream) {
  (void)n_in; (void)out_size; (void)ws_size;
  const float* hfeat = (const float*)d_in[0];
  const float* eij   = (const float*)d_in[1];
  const int*   src   = (const int*)d_in[2];
  const int*   dst   = (const int*)d_in[3];
  const float* W1    = (const float*)d_in[4];
  const float* b1    = (const float*)d_in[5];
  const float* W2    = (const float*)d_in[6];
  const float* b2    = (const float*)d_in[7];
  const float* gma   = (const float*)d_in[8];
  const float* bta   = (const float*)d_in[9];
  float* out = (float*)d_out;

  int N = in_sizes[0] / 128;
  int E = in_sizes[2];
  int q4 = N * 32;                                     // number of f4 chunks in h

  // workspace layout
  char* ws = (char*)d_ws;
  unsigned short* W1T = (unsigned short*)ws;              ws += 512 * 128 * 2;
  unsigned short* W2T = (unsigned short*)ws;              ws += 128 * 512 * 2;
  int* counts = (int*)ws;                                 ws += (size_t)N * 4;
  int* offs   = (int*)ws;                                 ws += (size_t)N * 4;
  ws = (char*)(((uintptr_t)ws + 255) & ~(uintptr_t)255);
  int2* perm2 = (int2*)ws;                                ws += (size_t)E * 8;
  unsigned short* hb = (unsigned short*)ws;               ws += (size_t)N * 128 * 2;
  unsigned short* ub = (unsigned short*)ws;               ws += (size_t)N * 128 * 2;

  prep_weights<<<256, 256, 0, stream>>>(W1, W2, W1T, W2T, counts, N);
  h2bf_hist<<<(q4 + 255) / 256, 256, 0, stream>>>(hfeat, hb, dst, counts, q4, E);
  scan_all<<<1, 1024, 0, stream>>>(counts, offs, N);
  build_perm<<<(E + 255) / 256, 256, 0, stream>>>(dst, src, offs, perm2, E);

  gather_sum<<<(N + 3) / 4, 256, 0, stream>>>(hb, eij, perm2, offs, counts,
                                              ub, N);

  fused_mlp_ln<<<(N + BM - 1) / BM, 256, 0, stream>>>(ub, hb, W1T, W2T,
                                                      b1, b2, gma, bta, out, N);
}

// Round 11
// 242.416 us; speedup vs baseline: 1.2713x; 1.2713x over previous
//
#include <hip/hip_runtime.h>

#define BM 64

typedef __bf16 bf16x8 __attribute__((ext_vector_type(8)));
typedef float f32x4 __attribute__((ext_vector_type(4)));
typedef float f4 __attribute__((ext_vector_type(4)));

__device__ __forceinline__ unsigned short f2bf(float x) {
  unsigned int u = __builtin_bit_cast(unsigned int, x);
  u += 0x7fffu + ((u >> 16) & 1u);   // RTNE
  return (unsigned short)(u >> 16);
}

__device__ __forceinline__ float bf1f(unsigned short x) {
  return __builtin_bit_cast(float, (unsigned)x << 16);
}

__device__ __forceinline__ int swz(int row, int col) {
  return (row * 128 + col) ^ ((row & 7) << 3);
}

__device__ __forceinline__ f4 ntload4(const float* p) {
  return __builtin_nontemporal_load((const f4*)p);
}

// 4 bf16 (as ushort4) -> 4 floats
__device__ __forceinline__ f4 bf4f(const unsigned short* p) {
  ushort4 v = *(const ushort4*)p;
  f4 r;
  r.x = bf1f(v.x); r.y = bf1f(v.y); r.z = bf1f(v.z); r.w = bf1f(v.w);
  return r;
}

__device__ __forceinline__ int wave_incl_scan(int v, int lane) {
  #pragma unroll
  for (int off = 1; off < 64; off <<= 1) {
    int t = __shfl_up(v, off, 64);
    if (lane >= off) v += t;
  }
  return v;
}

// ---- weights -> bf16 transposed; zero dst-degree counters ----
__global__ __launch_bounds__(256) void prep_weights(
    const float* __restrict__ W1, const float* __restrict__ W2,
    unsigned short* __restrict__ W1T, unsigned short* __restrict__ W2T,
    int* __restrict__ counts, int N) {
  int t = blockIdx.x * 256 + threadIdx.x;  // 0..65535
  if (t < N) counts[t] = 0;
  {  // W1 [128][512] -> W1T[h][k]
    int hh = t >> 7, kk = t & 127;
    W1T[t] = f2bf(W1[kk * 512 + hh]);
  }
  {  // W2 [512][128] -> W2T[d][h]
    int dd = t >> 9, hh = t & 511;
    W2T[t] = f2bf(W2[hh * 128 + dd]);
  }
}

// ---- h -> bf16 table, fused with dst histogram (counts pre-zeroed) ----
__global__ __launch_bounds__(256) void h2bf_hist(
    const float* __restrict__ h, unsigned short* __restrict__ hb,
    const int* __restrict__ dst, int* __restrict__ counts, int q4, int E) {
  int i = blockIdx.x * 256 + threadIdx.x;   // one f4 (4 elements) per thread
  if (i < q4) {
    f4 v = *(const f4*)(h + (size_t)i * 4);
    ushort4 o;
    o.x = f2bf(v.x); o.y = f2bf(v.y); o.z = f2bf(v.z); o.w = f2bf(v.w);
    *(ushort4*)(hb + (size_t)i * 4) = o;
  }
  if (i < E) atomicAdd(&counts[dst[i]], 1);
}

// ---- CSR scan: hierarchical (scan1/scan2/scan3 — known good) ----
__global__ __launch_bounds__(256) void scan1(const int* __restrict__ counts,
                                             int* offs, int* btot, int N) {
  int i = blockIdx.x * 256 + threadIdx.x;
  int lane = threadIdx.x & 63, wv = threadIdx.x >> 6;
  int v = (i < N) ? counts[i] : 0;
  int incl = wave_incl_scan(v, lane);
  __shared__ int wt[4];
  if (lane == 63) wt[wv] = incl;
  __syncthreads();
  int wpre = 0;
  for (int w = 0; w < wv; ++w) wpre += wt[w];
  if (i < N) offs[i] = wpre + incl - v;               // block-local exclusive
  if (threadIdx.x == 255) btot[blockIdx.x] = wpre + incl;
}

__global__ __launch_bounds__(64) void scan2(int* btot, int nb) {
  int lane = threadIdx.x;
  __shared__ int carry_s;
  if (lane == 0) carry_s = 0;
  __syncthreads();
  for (int base = 0; base < nb; base += 64) {
    int i = base + lane;
    int v = (i < nb) ? btot[i] : 0;
    int incl = wave_incl_scan(v, lane);
    int carry = carry_s;
    if (i < nb) btot[i] = carry + incl - v;            // exclusive
    __syncthreads();
    if (lane == 63) carry_s = carry + incl;
    __syncthreads();
  }
}

__global__ __launch_bounds__(256) void scan3(int* offs, const int* __restrict__ btot,
                                             int N) {
  int i = blockIdx.x * 256 + threadIdx.x;
  if (i < N) offs[i] += btot[blockIdx.x];
}

// bumps offs[] to row-end; gather recovers beg = end - cnt.
// perm2[p] = (edge index, src node) so the gather never chases src[].
__global__ __launch_bounds__(256) void build_perm(const int* __restrict__ dst,
                                                  const int* __restrict__ src,
                                                  int* offs, int2* perm2, int E) {
  int i = blockIdx.x * 256 + threadIdx.x;
  if (i < E) {
    int p = atomicAdd(&offs[dst[i]], 1);
    perm2[p] = make_int2(i, src[i]);
  }
}

// ---- ub[n] = bf16( sum over edges e with dst==n of (h[src[e]] + e_ij[e]) )
// Round-6 structure (known good): one wave per node, wave-uniform shfl
// bounds, 8-wide main loop. h read from the bf16 table (256B/row).
__global__ __launch_bounds__(256) void gather_sum(
    const unsigned short* __restrict__ hb, const float* __restrict__ eij,
    const int2* __restrict__ perm2,
    const int* __restrict__ offs, const int* __restrict__ counts,
    unsigned short* __restrict__ ub, int N) {
  int node = blockIdx.x * 4 + (threadIdx.x >> 6);
  if (node >= N) return;                               // wave-uniform
  int lane = threadIdx.x & 63;
  int half = lane >> 5, c4 = (lane & 31) * 4;
  int cnt = counts[node];
  int beg = offs[node] - cnt;                          // offs holds end after build_perm
  f4 acc = (f4){0.f, 0.f, 0.f, 0.f};
  for (int base = 0; base < cnt; base += 64) {
    int m = cnt - base; if (m > 64) m = 64;            // wave-uniform
    int2 es = perm2[beg + base + (lane < m ? lane : m - 1)];
    int k = 0;
    // main: 8 edges (4 per half) all provably in range for BOTH halves
    for (; 2 * k + 8 <= m; k += 4) {                   // uniform condition
      int i0 = 2 * k + half;
      int e0 = __shfl(es.x, i0, 64),     s0 = __shfl(es.y, i0, 64);
      int e1 = __shfl(es.x, i0 + 2, 64), s1 = __shfl(es.y, i0 + 2, 64);
      int e2 = __shfl(es.x, i0 + 4, 64), s2 = __shfl(es.y, i0 + 4, 64);
      int e3 = __shfl(es.x, i0 + 6, 64), s3 = __shfl(es.y, i0 + 6, 64);
      f4 ev0 = ntload4(eij + (size_t)e0 * 128 + c4);
      f4 ev1 = ntload4(eij + (size_t)e1 * 128 + c4);
      f4 ev2 = ntload4(eij + (size_t)e2 * 128 + c4);
      f4 ev3 = ntload4(eij + (size_t)e3 * 128 + c4);
      f4 hv0 = bf4f(hb + (size_t)s0 * 128 + c4);
      f4 hv1 = bf4f(hb + (size_t)s1 * 128 + c4);
      f4 hv2 = bf4f(hb + (size_t)s2 * 128 + c4);
      f4 hv3 = bf4f(hb + (size_t)s3 * 128 + c4);
      acc += (ev0 + hv0) + (ev1 + hv1) + (ev2 + hv2) + (ev3 + hv3);
    }
    // tail: uniform loop; shfl by all lanes, loads predicated
    for (; 2 * k < m; ++k) {                           // uniform condition
      int idx = 2 * k + half;
      int e = __shfl(es.x, idx & 63, 64), s = __shfl(es.y, idx & 63, 64);
      if (idx < m) {                                   // load-only divergence
        f4 ev = ntload4(eij + (size_t)e * 128 + c4);
        f4 hv = bf4f(hb + (size_t)s * 128 + c4);
        acc += ev + hv;
      }
    }
  }
  acc.x += __shfl_xor(acc.x, 32, 64);
  acc.y += __shfl_xor(acc.y, 32, 64);
  acc.z += __shfl_xor(acc.z, 32, 64);
  acc.w += __shfl_xor(acc.w, 32, 64);
  if (half == 0) {
    ushort4 o;
    o.x = f2bf(acc.x); o.y = f2bf(acc.y); o.z = f2bf(acc.z); o.w = f2bf(acc.w);
    *(ushort4*)(ub + (size_t)node * 128 + c4) = o;
  }
}

// ---- out = LN(relu(u@W1+b1)@W2 + b2 + h) * gamma + beta ----
// u read as bf16 from ub; residual h read as bf16 from hb.
__global__ __launch_bounds__(256, 2) void fused_mlp_ln(
    const unsigned short* __restrict__ ub, const unsigned short* __restrict__ hb,
    const unsigned short* __restrict__ W1T, const unsigned short* __restrict__ W2T,
    const float* __restrict__ b1, const float* __restrict__ b2,
    const float* __restrict__ gma, const float* __restrict__ bta,
    float* __restrict__ out, int N) {
  __shared__ unsigned short As[BM * 128];
  __shared__ unsigned short Hs[BM * 128];
  __shared__ unsigned short Bs[128 * 128];

  const int tid = threadIdx.x;
  const int wave = tid >> 6, lane = tid & 63;
  const int lo = lane & 15, hi = lane >> 4;
  const int bm0 = blockIdx.x * BM;
  const int arow = wave * 16 + lo;

  #pragma unroll
  for (int i = 0; i < 8; ++i) {
    int q = i * 256 + tid;
    int r = q >> 5, c4 = (q & 31) * 4;
    ushort4 v = make_ushort4(0, 0, 0, 0);
    if (bm0 + r < N) v = *(const ushort4*)(ub + (size_t)(bm0 + r) * 128 + c4);
    *(ushort4*)(&As[swz(r, c4)]) = v;
  }

  f32x4 acc2[8];
  #pragma unroll
  for (int n = 0; n < 8; ++n) acc2[n] = (f32x4){0.f, 0.f, 0.f, 0.f};

  for (int c = 0; c < 4; ++c) {
    __syncthreads();
    #pragma unroll
    for (int i = 0; i < 8; ++i) {
      int q = i * 256 + tid;
      int r = q >> 4, c8 = (q & 15) * 8;
      uint4 w = *(const uint4*)(W1T + ((size_t)(c * 128 + r) * 128 + c8));
      *(uint4*)(&Bs[swz(r, c8)]) = w;
    }
    __syncthreads();

    f32x4 acc1[8];
    #pragma unroll
    for (int n = 0; n < 8; ++n) acc1[n] = (f32x4){0.f, 0.f, 0.f, 0.f};
    #pragma unroll
    for (int kk = 0; kk < 4; ++kk) {
      bf16x8 a = *(const bf16x8*)(&As[swz(arow, kk * 32 + hi * 8)]);
      #pragma unroll
      for (int n = 0; n < 8; ++n) {
        bf16x8 b = *(const bf16x8*)(&Bs[swz(n * 16 + lo, kk * 32 + hi * 8)]);
        acc1[n] = __builtin_amdgcn_mfma_f32_16x16x32_bf16(a, b, acc1[n], 0, 0, 0);
      }
    }
    #pragma unroll
    for (int n = 0; n < 8; ++n) {
      float bb = b1[c * 128 + n * 16 + lo];
      #pragma unroll
      for (int j = 0; j < 4; ++j) {
        float v = acc1[n][j] + bb;
        v = v > 0.f ? v : 0.f;
        Hs[swz(wave * 16 + hi * 4 + j, n * 16 + lo)] = f2bf(v);
      }
    }
    __syncthreads();
    #pragma unroll
    for (int i = 0; i < 8; ++i) {
      int q = i * 256 + tid;
      int r = q >> 4, c8 = (q & 15) * 8;
      uint4 w = *(const uint4*)(W2T + ((size_t)r * 512 + c * 128 + c8));
      *(uint4*)(&Bs[swz(r, c8)]) = w;
    }
    __syncthreads();
    #pragma unroll
    for (int kk = 0; kk < 4; ++kk) {
      bf16x8 a = *(const bf16x8*)(&Hs[swz(arow, kk * 32 + hi * 8)]);
      #pragma unroll
      for (int n = 0; n < 8; ++n) {
        bf16x8 b = *(const bf16x8*)(&Bs[swz(n * 16 + lo, kk * 32 + hi * 8)]);
        acc2[n] = __builtin_amdgcn_mfma_f32_16x16x32_bf16(a, b, acc2[n], 0, 0, 0);
      }
    }
  }

  float b2v[8], gv[8], bv2[8];
  #pragma unroll
  for (int n = 0; n < 8; ++n) {
    int d = n * 16 + lo;
    b2v[n] = b2[d]; gv[n] = gma[d]; bv2[n] = bta[d];
  }
  #pragma unroll
  for (int j = 0; j < 4; ++j) {
    int m = wave * 16 + hi * 4 + j;
    int grow = bm0 + m;
    bool valid = grow < N;
    float vals[8];
    float s = 0.f, s2 = 0.f;
    #pragma unroll
    for (int n = 0; n < 8; ++n) {
      float hres = valid ? bf1f(hb[(size_t)grow * 128 + n * 16 + lo]) : 0.f;
      float v = acc2[n][j] + b2v[n] + hres;
      vals[n] = v;
      s += v; s2 += v * v;
    }
    #pragma unroll
    for (int mk = 1; mk < 16; mk <<= 1) {
      s  += __shfl_xor(s, mk, 64);
      s2 += __shfl_xor(s2, mk, 64);
    }
    float mean = s * (1.f / 128.f);
    float var = s2 * (1.f / 128.f) - mean * mean;
    float inv = rsqrtf(var + 1e-5f);
    if (valid) {
      #pragma unroll
      for (int n = 0; n < 8; ++n) {
        out[(size_t)grow * 128 + n * 16 + lo] = (vals[n] - mean) * inv * gv[n] + bv2[n];
      }
    }
  }
}

extern "C" void kernel_launch(void* const* d_in, const int* in_sizes, int n_in,
                              void* d_out, int out_size, void* d_ws, size_t ws_size,
                              hipStream_t stream) {
  (void)n_in; (void)out_size; (void)ws_size;
  const float* hfeat = (const float*)d_in[0];
  const float* eij   = (const float*)d_in[1];
  const int*   src   = (const int*)d_in[2];
  const int*   dst   = (const int*)d_in[3];
  const float* W1    = (const float*)d_in[4];
  const float* b1    = (const float*)d_in[5];
  const float* W2    = (const float*)d_in[6];
  const float* b2    = (const float*)d_in[7];
  const float* gma   = (const float*)d_in[8];
  const float* bta   = (const float*)d_in[9];
  float* out = (float*)d_out;

  int N = in_sizes[0] / 128;
  int E = in_sizes[2];
  int nb1 = (N + 255) / 256;
  int q4 = N * 32;                                     // number of f4 chunks in h

  // workspace layout
  char* ws = (char*)d_ws;
  unsigned short* W1T = (unsigned short*)ws;              ws += 512 * 128 * 2;
  unsigned short* W2T = (unsigned short*)ws;              ws += 128 * 512 * 2;
  int* counts = (int*)ws;                                 ws += (size_t)N * 4;
  int* offs   = (int*)ws;                                 ws += (size_t)N * 4;
  int* btot   = (int*)ws;                                 ws += ((nb1 + 63) / 64) * 64 * 4;
  ws = (char*)(((uintptr_t)ws + 255) & ~(uintptr_t)255);
  int2* perm2 = (int2*)ws;                                ws += (size_t)E * 8;
  unsigned short* hb = (unsigned short*)ws;               ws += (size_t)N * 128 * 2;
  unsigned short* ub = (unsigned short*)ws;               ws += (size_t)N * 128 * 2;

  prep_weights<<<256, 256, 0, stream>>>(W1, W2, W1T, W2T, counts, N);
  h2bf_hist<<<(q4 + 255) / 256, 256, 0, stream>>>(hfeat, hb, dst, counts, q4, E);
  scan1<<<nb1, 256, 0, stream>>>(counts, offs, btot, N);
  scan2<<<1, 64, 0, stream>>>(btot, nb1);
  scan3<<<nb1, 256, 0, stream>>>(offs, btot, N);
  build_perm<<<(E + 255) / 256, 256, 0, stream>>>(dst, src, offs, perm2, E);

  gather_sum<<<(N + 3) / 4, 256, 0, stream>>>(hb, eij, perm2, offs, counts,
                                              ub, N);

  fused_mlp_ln<<<(N + BM - 1) / BM, 256, 0, stream>>>(ub, hb, W1T, W2T,
                                                      b1, b2, gma, bta, out, N);
}